// Round 7
// baseline (176.102 us; speedup 1.0000x reference)
//
#include <hip/hip_runtime.h>
#include <hip/hip_fp16.h>

#define BATCH 16
#define C_IN  64
#define HH    64
#define WW    64
#define COUT  64
#define KK    9
#define HW    4096
#define CK    576
#define WROWS 15    // staged window rows: [R4-5, R4+9] for rows R4..R4+3
#define WLO   5

typedef _Float16 f16x8 __attribute__((ext_vector_type(8)));
typedef float    f32x4 __attribute__((ext_vector_type(4)));

__device__ __forceinline__ unsigned short f32_to_f16u(float f) {
    _Float16 h = (_Float16)f;       // v_cvt_f16_f32, RNE
    unsigned short u;
    __builtin_memcpy(&u, &h, 2);
    return u;
}

__device__ __forceinline__ __half2 as_h2(unsigned int u) {
    __half2 r; __builtin_memcpy(&r, &u, 4); return r;
}
__device__ __forceinline__ unsigned int as_u32(__half2 v) {
    unsigned int u; __builtin_memcpy(&u, &v, 4); return u;
}

// Fused prep (R10 version, byte-identical — measured part of the 96.75 anchor).
// Blocks 0..1023: x (B,C,H,W) f32 -> xt (B,H,W,C) f16.
// Blocks 1024..1167: w (Cout,C,3,3) f32 -> wt in MFMA A-fragment order (f16).
__global__ __launch_bounds__(256) void prep_kernel(
    const float* __restrict__ x, const float* __restrict__ w,
    unsigned short* __restrict__ xt, unsigned short* __restrict__ wt) {
    __shared__ unsigned short tile[64][72];
    const int t = threadIdx.x;
    const int blk = blockIdx.x;
    if (blk < 1024) {
        const int b = blk >> 6, y = blk & 63;
        const float* xrow = x + ((b * 64) * 64 + y) * 64;
#pragma unroll
        for (int it = 0; it < 4; ++it) {
            const int idx = it * 256 + t;
            const int c = idx >> 4, seg = idx & 15;
            const float4 v = *(const float4*)(xrow + c * HW + seg * 4);
            tile[seg * 4 + 0][c] = f32_to_f16u(v.x);
            tile[seg * 4 + 1][c] = f32_to_f16u(v.y);
            tile[seg * 4 + 2][c] = f32_to_f16u(v.z);
            tile[seg * 4 + 3][c] = f32_to_f16u(v.w);
        }
        __syncthreads();
#pragma unroll
        for (int it = 0; it < 2; ++it) {
            const int idx = it * 256 + t;
            const int xx = idx >> 3, cs = idx & 7;
            *(int4*)&xt[((b * HW) + y * 64 + xx) * 64 + cs * 8] =
                *(const int4*)&tile[xx][cs * 8];
        }
    } else {
        const int i = (blk - 1024) * 256 + t;  // 0..36863
        const int j = i & 7;
        const int l = (i >> 3) & 63;
        const int ot = (i >> 9) & 3;
        const int r = i >> 11;           // 0..17
        const int ks = r % 6, kc = r / 6;
        const int o  = ot * 16 + (l & 15);
        const int kk = ks * 32 + (l >> 4) * 8 + j;
        const int tap = kk >> 6, c = kk & 63;
        const int k = kc * 3 + tap;
        wt[i] = f32_to_f16u(w[o * CK + c * KK + k]);
    }
}

// Main, R14.  Grid 256 = exactly 1 block/CU, ONE round, ONE __syncthreads.
// R13 post-mortem: gather pre-issue neutral => latency not binding; the
// residual is the 2-round serial structure (each round: serial prologue +
// staging drain with all pipes idle).  R14: block = 8 waves owns FOUR rows,
// one 15-row window [R4-5,R4+9] (122.9 KB).  Params for ALL 4 rows are
// computed in the single prologue and PACKED to 8 B each (weights 4xf16,
// addrs 4xu16 pre-swizzled-offset/16) so they fit: 36.9 KB + window =
// 159.7 KB <= 160 KiB.  vs R10: one prologue instead of two, 15 staged rows
// instead of 26, no second launch round, no mid-kernel syncs (R11's flaw).
// Unpack cost: ~2 VALU/corner + 2 VALU/weight (CSE'd across ks pairs).
// Escape (|oy|>~4, P~6e-5): exact recompute + global fallback, ~never taken.
__global__ __launch_bounds__(512, 1) void dcn_main_kernel(
    const float* __restrict__ offset, const float* __restrict__ mask,
    const unsigned short* __restrict__ xt, const unsigned short* __restrict__ wt,
    const float* __restrict__ bias, float* __restrict__ out) {
    __shared__ __align__(16) unsigned short win[WROWS * 4096];   // 122880 B
    __shared__ __align__(8) uint2 PWw[4][576];                   //  18432 B
    __shared__ __align__(8) uint2 PWa[4][576];                   //  18432 B
                                                                 // 159744 B

    const int t    = threadIdx.x;
    const int wave = __builtin_amdgcn_readfirstlane(t >> 6);
    const int lane = t & 63;
    const int quad = lane >> 4, m16 = lane & 15;
    const int rw   = wave >> 2;          // row within pair
    const int qb   = (wave & 3) * 16;    // px strip base

    const int blk = blockIdx.x;          // 0..255
    const int xcd = blk & 7;             // L2 image pinning (R2 win)
    const int i5  = blk >> 3;            // 0..31 within XCD
    const int b   = (xcd << 1) | (i5 >> 4);
    const int R4  = (i5 & 15) * 4;       // first of the 4 rows
    const int base = R4 - WLO;           // window first row (may be <0)

    const float* offb = offset + b * (2 * KK * HW);
    const float* mb   = mask + b * (KK * HW);
    const char* xtb   = (const char*)(xt + b * (HW * 64));

    // ---- Prologue loads first (params vmem oldest; staging stays in
    //      flight under the params compute).  2304 items = 9 taps x 4 rows
    //      x 64 q; it -> (tap=it>>8, rowi=(it>>6)&3, q=it&63). ----
    float oyv[5], oxv[5], mkv[5];
#pragma unroll
    for (int p = 0; p < 5; ++p) {
        const int it = p * 512 + t;
        if (it < 2304) {
            const int tap = it >> 8, rowi = (it >> 6) & 3, q = it & 63;
            const int rowX = R4 + rowi;
            oyv[p] = offb[(2 * tap) * HW + rowX * 64 + q];
            oxv[p] = offb[(2 * tap + 1) * HW + rowX * 64 + q];
            mkv[p] = mb[tap * HW + rowX * 64 + q];
        } else { oyv[p] = 0.f; oxv[p] = 0.f; mkv[p] = 0.f; }
    }
    asm volatile("" :: "v"(oyv[0]), "v"(oxv[0]), "v"(mkv[0]),
                       "v"(oyv[1]), "v"(oxv[1]), "v"(mkv[1]),
                       "v"(oyv[2]), "v"(oxv[2]), "v"(mkv[2]));
    asm volatile("" :: "v"(oyv[3]), "v"(oxv[3]), "v"(mkv[3]),
                       "v"(oyv[4]), "v"(oxv[4]), "v"(mkv[4]));

    // ---- Stage window: 15 rows x 8 KB, async global->LDS, swizzled source.
    //      LDS dest linear (HW rule); global source carries the inverse
    //      swizzle: chan-block s' of pixel pxl holds global s' ^ (pxl&7). ----
    const int pxl = t >> 3;
    const int swb = ((t & 7) ^ (pxl & 7)) << 4;
#pragma unroll
    for (int s = 0; s < WROWS; ++s) {
        const int srcrow = min(max(base + s, 0), HH - 1);
        const char* src = xtb + srcrow * 8192 + pxl * 128 + swb;
        __builtin_amdgcn_global_load_lds(
            (const __attribute__((address_space(1))) unsigned int*)src,
            (__attribute__((address_space(3))) unsigned int*)
                ((char*)win + s * 8192 + t * 16),
            16, 0, 0);
    }
    __builtin_amdgcn_sched_barrier(0);

    // ---- Prologue compute: packed params for all 2304 items ----
    //      PWa: 4 x u16, e(w) = (w<<3)|(w&7) (pre-swizzled byteoff>>4);
    //           esc flag in bit 15 of the first u16.
    //      PWw: 4 x f16 bilinear weights (duplicated to half2 at use).
#pragma unroll
    for (int p = 0; p < 5; ++p) {
        const int it = p * 512 + t;
        if (it < 2304) {
            const int tap = it >> 8, rowi = (it >> 6) & 3, q = it & 63;
            const int rowX = R4 + rowi;
            const int ky = (tap * 11) >> 5;      // tap/3 for 0..8
            const int kx = tap - ky * 3;
            const float py  = oyv[p] + (float)(rowX - 1 + ky);
            const float pxf = oxv[p] + (float)(q - 1 + kx);
            const float y0f = floorf(py), x0f = floorf(pxf);
            const float wy = py - y0f, wx = pxf - x0f;
            const int y0 = (int)y0f, x0 = (int)x0f;
            const int y1 = y0 + 1,   x1 = x0 + 1;
            const float vy0 = (y0 >= 0 && y0 < HH) ? 1.f : 0.f;
            const float vy1 = (y1 >= 0 && y1 < HH) ? 1.f : 0.f;
            const float vx0 = (x0 >= 0 && x0 < WW) ? 1.f : 0.f;
            const float vx1 = (x1 >= 0 && x1 < WW) ? 1.f : 0.f;
            const float mk = mkv[p];
            const float w00 = (1.f - wy) * (1.f - wx) * vy0 * vx0 * mk;
            const float w01 = (1.f - wy) * wx         * vy0 * vx1 * mk;
            const float w10 = wy * (1.f - wx)         * vy1 * vx0 * mk;
            const float w11 = wy * wx                 * vy1 * vx1 * mk;
            const int cy0 = min(max(y0, 0), HH - 1), cy1 = min(max(y1, 0), HH - 1);
            const int cx0 = min(max(x0, 0), WW - 1), cx1 = min(max(x1, 0), WW - 1);
            const int sl0 = cy0 - base, sl1 = cy1 - base;
            const unsigned esc = (sl0 < 0) | (sl1 > (WROWS - 1));
            const int c0 = min(max(sl0, 0), WROWS - 1);
            const int c1 = min(max(sl1, 0), WROWS - 1);
            const int wl00 = c0 * 64 + cx0, wl01 = c0 * 64 + cx1;
            const int wl10 = c1 * 64 + cx0, wl11 = c1 * 64 + cx1;
            const unsigned e00 = (unsigned)((wl00 << 3) | (wl00 & 7)) | (esc << 15);
            const unsigned e01 = (unsigned)((wl01 << 3) | (wl01 & 7));
            const unsigned e10 = (unsigned)((wl10 << 3) | (wl10 & 7));
            const unsigned e11 = (unsigned)((wl11 << 3) | (wl11 & 7));
            const unsigned s00 = f32_to_f16u(w00);
            const unsigned s01 = f32_to_f16u(w01);
            const unsigned s10 = f32_to_f16u(w10);
            const unsigned s11 = f32_to_f16u(w11);
            uint2 Wp; Wp.x = s00 | (s01 << 16); Wp.y = s10 | (s11 << 16);
            uint2 Aa; Aa.x = e00 | (e01 << 16); Aa.y = e10 | (e11 << 16);
            PWw[rowi][tap * 64 + q] = Wp;
            PWa[rowi][tap * 64 + q] = Aa;
        }
    }
    __syncthreads();   // staging (per-wave vmcnt) + all params visible

    const char* winc = (const char*)win;

#pragma unroll 1
    for (int pr = 0; pr < 2; ++pr) {
        f32x4 acc[4];
#pragma unroll
        for (int ot = 0; ot < 4; ++ot)
#pragma unroll
            for (int r = 0; r < 4; ++r) acc[ot][r] = 0.f;

        const int arow = pr * 2 + rw;        // 0..3
        const int rowX = R4 + arow;

#pragma unroll
        for (int kc = 0; kc < 3; ++kc) {
            const unsigned short* wkc = wt + kc * (6 * 4 * 512);

            // ---- phase A: the 3 distinct packed param pairs ----
            uint2 A3[3], W3[3];
#pragma unroll
            for (int tp = 0; tp < 3; ++tp) {
                const int it = (kc * 3 + tp) * 64 + qb + m16;
                A3[tp] = PWa[arow][it];      // bcast x4
                W3[tp] = PWw[arow][it];      // bcast x4
            }

            // ---- phase B: issue all 24 gather ds_read_b128 ----
            uint4 qv[6][4];
#pragma unroll
            for (int ks = 0; ks < 6; ++ks) {
                const int tp = ks >> 1;
                const unsigned sswz = (unsigned)(((ks & 1) * 4 + quad) << 4);
                const unsigned e00 = A3[tp].x & 0x7FFFu;
                const unsigned e01 = A3[tp].x >> 16;
                const unsigned e10 = A3[tp].y & 0xFFFFu;
                const unsigned e11 = A3[tp].y >> 16;
                qv[ks][0] = *(const uint4*)(winc + ((e00 << 4) ^ sswz));
                qv[ks][1] = *(const uint4*)(winc + ((e01 << 4) ^ sswz));
                qv[ks][2] = *(const uint4*)(winc + ((e10 << 4) ^ sswz));
                qv[ks][3] = *(const uint4*)(winc + ((e11 << 4) ^ sswz));
            }

            // ---- escape fixup (rare: |oy| beyond window reach) ----
            const int anyesc =
                (int)(((A3[0].x | A3[1].x | A3[2].x) >> 15) & 1u);
            if (__builtin_expect(__any(anyesc), 0)) {
#pragma unroll
                for (int ks = 0; ks < 6; ++ks) {
                    const int tp = ks >> 1;
                    if ((A3[tp].x >> 15) & 1u) {
                        const int tap = kc * 3 + tp;
                        const int qq = qb + m16;
                        const int ky = (tap * 11) >> 5;
                        const int kx = tap - ky * 3;
                        const float oy = offb[(2 * tap) * HW + rowX * 64 + qq];
                        const float ox = offb[(2 * tap + 1) * HW + rowX * 64 + qq];
                        const float py  = oy + (float)(rowX - 1 + ky);
                        const float pxf = ox + (float)(qq - 1 + kx);
                        const int y0 = (int)floorf(py), x0 = (int)floorf(pxf);
                        const int cy0 = min(max(y0, 0), HH - 1);
                        const int cy1 = min(max(y0 + 1, 0), HH - 1);
                        const int cx0 = min(max(x0, 0), WW - 1);
                        const int cx1 = min(max(x0 + 1, 0), WW - 1);
                        const int hoff = (ks & 1) * 64 + quad * 16;
                        qv[ks][0] = *(const uint4*)(xtb + ((cy0 * 64 + cx0) << 7) + hoff);
                        qv[ks][1] = *(const uint4*)(xtb + ((cy0 * 64 + cx1) << 7) + hoff);
                        qv[ks][2] = *(const uint4*)(xtb + ((cy1 * 64 + cx0) << 7) + hoff);
                        qv[ks][3] = *(const uint4*)(xtb + ((cy1 * 64 + cx1) << 7) + hoff);
                    }
                }
            }

            // ---- phase C: combine + MFMA, all 6 ks-steps ----
#pragma unroll
            for (int ks = 0; ks < 6; ++ks) {
                const uint2 Wp = W3[ks >> 1];
                unsigned ulo = Wp.x & 0xFFFFu;            // CSE'd across ks pair
                const __half2 c00 = as_h2(ulo | (ulo << 16));
                unsigned uhi = Wp.x >> 16;
                const __half2 c01 = as_h2(uhi | (uhi << 16));
                unsigned vlo = Wp.y & 0xFFFFu;
                const __half2 c10 = as_h2(vlo | (vlo << 16));
                unsigned vhi = Wp.y >> 16;
                const __half2 c11 = as_h2(vhi | (vhi << 16));
                const uint4 q0 = qv[ks][0], q1 = qv[ks][1];
                const uint4 q2 = qv[ks][2], q3 = qv[ks][3];
                uint4 ov;
                {
                    __half2 v = __hmul2(c00, as_h2(q0.x));
                    v = __hfma2(c01, as_h2(q1.x), v);
                    v = __hfma2(c10, as_h2(q2.x), v);
                    v = __hfma2(c11, as_h2(q3.x), v);
                    ov.x = as_u32(v);
                }
                {
                    __half2 v = __hmul2(c00, as_h2(q0.y));
                    v = __hfma2(c01, as_h2(q1.y), v);
                    v = __hfma2(c10, as_h2(q2.y), v);
                    v = __hfma2(c11, as_h2(q3.y), v);
                    ov.y = as_u32(v);
                }
                {
                    __half2 v = __hmul2(c00, as_h2(q0.z));
                    v = __hfma2(c01, as_h2(q1.z), v);
                    v = __hfma2(c10, as_h2(q2.z), v);
                    v = __hfma2(c11, as_h2(q3.z), v);
                    ov.z = as_u32(v);
                }
                {
                    __half2 v = __hmul2(c00, as_h2(q0.w));
                    v = __hfma2(c01, as_h2(q1.w), v);
                    v = __hfma2(c10, as_h2(q2.w), v);
                    v = __hfma2(c11, as_h2(q3.w), v);
                    ov.w = as_u32(v);
                }
                f16x8 bfrag;
                __builtin_memcpy(&bfrag, &ov, 16);
#pragma unroll
                for (int ot = 0; ot < 4; ++ot) {
                    const f16x8 afrag =
                        *(const f16x8*)(wkc + (ks * 4 + ot) * 512 + lane * 8);
                    acc[ot] = __builtin_amdgcn_mfma_f32_16x16x32_f16(
                        afrag, bfrag, acc[ot], 0, 0, 0);
                }
            }
        }

        float* ob = out + b * (COUT * HW) + rowX * 64 + qb + m16;
#pragma unroll
        for (int ot = 0; ot < 4; ++ot)
#pragma unroll
            for (int r = 0; r < 4; ++r) {
                const int o = ot * 16 + quad * 4 + r;
                ob[o * HW] = acc[ot][r] + bias[o];
            }
    }
}

extern "C" void kernel_launch(void* const* d_in, const int* in_sizes, int n_in,
                              void* d_out, int out_size, void* d_ws,
                              size_t ws_size, hipStream_t stream) {
    const float* x    = (const float*)d_in[0];
    const float* off  = (const float*)d_in[1];
    const float* mask = (const float*)d_in[2];
    const float* w    = (const float*)d_in[3];
    const float* bias = (const float*)d_in[4];
    float* out = (float*)d_out;

    unsigned short* xt = (unsigned short*)d_ws;                     // 8388608 B
    unsigned short* wt = (unsigned short*)((char*)d_ws + 8388608);  // 73728 B

    prep_kernel<<<1024 + 144, 256, 0, stream>>>(x, w, xt, wt);
    dcn_main_kernel<<<256, 512, 0, stream>>>(off, mask, xt, wt, bias, out);
}

// Round 8
// 125.318 us; speedup vs baseline: 1.4052x; 1.4052x over previous
//
#include <hip/hip_runtime.h>
#include <hip/hip_fp16.h>

#define BATCH 16
#define C_IN  64
#define HH    64
#define WW    64
#define COUT  64
#define KK    9
#define HW    4096
#define CK    576
#define WROWS 15    // staged window rows: [R4-5, R4+9] for rows R4..R4+3
#define WLO   5

typedef _Float16 f16x8 __attribute__((ext_vector_type(8)));
typedef float    f32x4 __attribute__((ext_vector_type(4)));

__device__ __forceinline__ unsigned short f32_to_f16u(float f) {
    _Float16 h = (_Float16)f;       // v_cvt_f16_f32, RNE
    unsigned short u;
    __builtin_memcpy(&u, &h, 2);
    return u;
}

__device__ __forceinline__ __half2 as_h2(unsigned int u) {
    __half2 r; __builtin_memcpy(&r, &u, 4); return r;
}
__device__ __forceinline__ unsigned int as_u32(__half2 v) {
    unsigned int u; __builtin_memcpy(&u, &v, 4); return u;
}

// Fused prep (R10 version, byte-identical — measured part of the 96.75 anchor).
// Blocks 0..1023: x (B,C,H,W) f32 -> xt (B,H,W,C) f16.
// Blocks 1024..1167: w (Cout,C,3,3) f32 -> wt in MFMA A-fragment order (f16).
__global__ __launch_bounds__(256) void prep_kernel(
    const float* __restrict__ x, const float* __restrict__ w,
    unsigned short* __restrict__ xt, unsigned short* __restrict__ wt) {
    __shared__ unsigned short tile[64][72];
    const int t = threadIdx.x;
    const int blk = blockIdx.x;
    if (blk < 1024) {
        const int b = blk >> 6, y = blk & 63;
        const float* xrow = x + ((b * 64) * 64 + y) * 64;
#pragma unroll
        for (int it = 0; it < 4; ++it) {
            const int idx = it * 256 + t;
            const int c = idx >> 4, seg = idx & 15;
            const float4 v = *(const float4*)(xrow + c * HW + seg * 4);
            tile[seg * 4 + 0][c] = f32_to_f16u(v.x);
            tile[seg * 4 + 1][c] = f32_to_f16u(v.y);
            tile[seg * 4 + 2][c] = f32_to_f16u(v.z);
            tile[seg * 4 + 3][c] = f32_to_f16u(v.w);
        }
        __syncthreads();
#pragma unroll
        for (int it = 0; it < 2; ++it) {
            const int idx = it * 256 + t;
            const int xx = idx >> 3, cs = idx & 7;
            *(int4*)&xt[((b * HW) + y * 64 + xx) * 64 + cs * 8] =
                *(const int4*)&tile[xx][cs * 8];
        }
    } else {
        const int i = (blk - 1024) * 256 + t;  // 0..36863
        const int j = i & 7;
        const int l = (i >> 3) & 63;
        const int ot = (i >> 9) & 3;
        const int r = i >> 11;           // 0..17
        const int ks = r % 6, kc = r / 6;
        const int o  = ot * 16 + (l & 15);
        const int kk = ks * 32 + (l >> 4) * 8 + j;
        const int tap = kk >> 6, c = kk & 63;
        const int k = kc * 3 + tap;
        wt[i] = f32_to_f16u(w[o * CK + c * KK + k]);
    }
}

// Main, R15 = R14 structure + R10 inner loop (spill-proof).
// R14 post-mortem: main FETCH 120 MB / WRITE 130 MB @ VGPR=128 = scratch
// spill of the qv[6][4] gather register file; the single-round structure was
// never actually tested.  R15 keeps the merge (grid 256 = 1 block/CU, ONE
// prologue, ONE __syncthreads, 15 staged rows vs 26, packed 8-B params for
// all 4 rows: window 122.9K + params 36.9K = 159.7 KB LDS) but gathers are
// per-ks inline (no register batching — R13 proved batching neutral), so the
// live set stays ~R10's 88-105 VGPR.  Escape (|oy|>~4, P~6e-5): exact
// recompute + global fallback, ~never taken.
__global__ __launch_bounds__(512, 1) void dcn_main_kernel(
    const float* __restrict__ offset, const float* __restrict__ mask,
    const unsigned short* __restrict__ xt, const unsigned short* __restrict__ wt,
    const float* __restrict__ bias, float* __restrict__ out) {
    __shared__ __align__(16) unsigned short win[WROWS * 4096];   // 122880 B
    __shared__ __align__(8) uint2 PWw[4][576];                   //  18432 B
    __shared__ __align__(8) uint2 PWa[4][576];                   //  18432 B
                                                                 // 159744 B

    const int t    = threadIdx.x;
    const int wave = __builtin_amdgcn_readfirstlane(t >> 6);
    const int lane = t & 63;
    const int quad = lane >> 4, m16 = lane & 15;
    const int rw   = wave >> 2;          // row within pair
    const int qb   = (wave & 3) * 16;    // px strip base

    const int blk = blockIdx.x;          // 0..255
    const int xcd = blk & 7;             // L2 image pinning (R2 win)
    const int i5  = blk >> 3;            // 0..31 within XCD
    const int b   = (xcd << 1) | (i5 >> 4);
    const int R4  = (i5 & 15) * 4;       // first of the 4 rows
    const int base = R4 - WLO;           // window first row (may be <0)

    const float* offb = offset + b * (2 * KK * HW);
    const float* mb   = mask + b * (KK * HW);
    const char* xtb   = (const char*)(xt + b * (HW * 64));

    // ---- Prologue loads first (params vmem oldest; staging stays in
    //      flight under the params compute).  2304 items = 9 taps x 4 rows
    //      x 64 q; it -> (tap=it>>8, rowi=(it>>6)&3, q=it&63). ----
    float oyv[5], oxv[5], mkv[5];
#pragma unroll
    for (int p = 0; p < 5; ++p) {
        const int it = p * 512 + t;
        if (it < 2304) {
            const int tap = it >> 8, rowi = (it >> 6) & 3, q = it & 63;
            const int rowX = R4 + rowi;
            oyv[p] = offb[(2 * tap) * HW + rowX * 64 + q];
            oxv[p] = offb[(2 * tap + 1) * HW + rowX * 64 + q];
            mkv[p] = mb[tap * HW + rowX * 64 + q];
        } else { oyv[p] = 0.f; oxv[p] = 0.f; mkv[p] = 0.f; }
    }
    asm volatile("" :: "v"(oyv[0]), "v"(oxv[0]), "v"(mkv[0]),
                       "v"(oyv[1]), "v"(oxv[1]), "v"(mkv[1]),
                       "v"(oyv[2]), "v"(oxv[2]), "v"(mkv[2]));
    asm volatile("" :: "v"(oyv[3]), "v"(oxv[3]), "v"(mkv[3]),
                       "v"(oyv[4]), "v"(oxv[4]), "v"(mkv[4]));

    // ---- Stage window: 15 rows x 8 KB, async global->LDS, swizzled source.
    //      LDS dest linear (HW rule); global source carries the inverse
    //      swizzle: chan-block s' of pixel pxl holds global s' ^ (pxl&7). ----
    const int pxl = t >> 3;
    const int swb = ((t & 7) ^ (pxl & 7)) << 4;
#pragma unroll
    for (int s = 0; s < WROWS; ++s) {
        const int srcrow = min(max(base + s, 0), HH - 1);
        const char* src = xtb + srcrow * 8192 + pxl * 128 + swb;
        __builtin_amdgcn_global_load_lds(
            (const __attribute__((address_space(1))) unsigned int*)src,
            (__attribute__((address_space(3))) unsigned int*)
                ((char*)win + s * 8192 + t * 16),
            16, 0, 0);
    }
    __builtin_amdgcn_sched_barrier(0);

    // ---- Prologue compute: packed params for all 2304 items ----
    //      PWa: 4 x u16, e(w) = (w<<3)|(w&7) (pre-swizzled byteoff>>4);
    //           esc flag in bit 15 of the first u16.  (w<<3 <= 8184 < 2^15.)
    //      PWw: 4 x f16 bilinear weights (dup'd to half2 at use).
#pragma unroll
    for (int p = 0; p < 5; ++p) {
        const int it = p * 512 + t;
        if (it < 2304) {
            const int tap = it >> 8, rowi = (it >> 6) & 3, q = it & 63;
            const int rowX = R4 + rowi;
            const int ky = (tap * 11) >> 5;      // tap/3 for 0..8
            const int kx = tap - ky * 3;
            const float py  = oyv[p] + (float)(rowX - 1 + ky);
            const float pxf = oxv[p] + (float)(q - 1 + kx);
            const float y0f = floorf(py), x0f = floorf(pxf);
            const float wy = py - y0f, wx = pxf - x0f;
            const int y0 = (int)y0f, x0 = (int)x0f;
            const int y1 = y0 + 1,   x1 = x0 + 1;
            const float vy0 = (y0 >= 0 && y0 < HH) ? 1.f : 0.f;
            const float vy1 = (y1 >= 0 && y1 < HH) ? 1.f : 0.f;
            const float vx0 = (x0 >= 0 && x0 < WW) ? 1.f : 0.f;
            const float vx1 = (x1 >= 0 && x1 < WW) ? 1.f : 0.f;
            const float mk = mkv[p];
            const float w00 = (1.f - wy) * (1.f - wx) * vy0 * vx0 * mk;
            const float w01 = (1.f - wy) * wx         * vy0 * vx1 * mk;
            const float w10 = wy * (1.f - wx)         * vy1 * vx0 * mk;
            const float w11 = wy * wx                 * vy1 * vx1 * mk;
            const int cy0 = min(max(y0, 0), HH - 1), cy1 = min(max(y1, 0), HH - 1);
            const int cx0 = min(max(x0, 0), WW - 1), cx1 = min(max(x1, 0), WW - 1);
            const int sl0 = cy0 - base, sl1 = cy1 - base;
            const unsigned esc = (sl0 < 0) | (sl1 > (WROWS - 1));
            const int c0 = min(max(sl0, 0), WROWS - 1);
            const int c1 = min(max(sl1, 0), WROWS - 1);
            const int wl00 = c0 * 64 + cx0, wl01 = c0 * 64 + cx1;
            const int wl10 = c1 * 64 + cx0, wl11 = c1 * 64 + cx1;
            const unsigned e00 = (unsigned)((wl00 << 3) | (wl00 & 7)) | (esc << 15);
            const unsigned e01 = (unsigned)((wl01 << 3) | (wl01 & 7));
            const unsigned e10 = (unsigned)((wl10 << 3) | (wl10 & 7));
            const unsigned e11 = (unsigned)((wl11 << 3) | (wl11 & 7));
            const unsigned s00 = f32_to_f16u(w00);
            const unsigned s01 = f32_to_f16u(w01);
            const unsigned s10 = f32_to_f16u(w10);
            const unsigned s11 = f32_to_f16u(w11);
            uint2 Wp; Wp.x = s00 | (s01 << 16); Wp.y = s10 | (s11 << 16);
            uint2 Aa; Aa.x = e00 | (e01 << 16); Aa.y = e10 | (e11 << 16);
            PWw[rowi][tap * 64 + q] = Wp;
            PWa[rowi][tap * 64 + q] = Aa;
        }
    }
    __syncthreads();   // staging (per-wave vmcnt) + all params visible

    const char* winc = (const char*)win;

#pragma unroll 1
    for (int pr = 0; pr < 2; ++pr) {
        f32x4 acc[4];
#pragma unroll
        for (int ot = 0; ot < 4; ++ot)
#pragma unroll
            for (int r = 0; r < 4; ++r) acc[ot][r] = 0.f;

        const int arow = pr * 2 + rw;        // 0..3
        const int rowX = R4 + arow;

#pragma unroll
        for (int kc = 0; kc < 3; ++kc) {
            const unsigned short* wkc = wt + kc * (6 * 4 * 512);

            // ---- hoist the 3 distinct packed params of this chunk ----
            uint2 A3[3];
            __half2 ch[3][4];
#pragma unroll
            for (int tp = 0; tp < 3; ++tp) {
                const int it = (kc * 3 + tp) * 64 + qb + m16;
                A3[tp] = PWa[arow][it];          // bcast x4
                const uint2 Wp = PWw[arow][it];  // bcast x4
                const unsigned ulo = Wp.x & 0xFFFFu;
                const unsigned uhi = Wp.x >> 16;
                const unsigned vlo = Wp.y & 0xFFFFu;
                const unsigned vhi = Wp.y >> 16;
                ch[tp][0] = as_h2(ulo | (ulo << 16));
                ch[tp][1] = as_h2(uhi | (uhi << 16));
                ch[tp][2] = as_h2(vlo | (vlo << 16));
                ch[tp][3] = as_h2(vhi | (vhi << 16));
            }

            // ---- per-ks: inline gather -> combine -> MFMA (R10 style) ----
#pragma unroll
            for (int ks = 0; ks < 6; ++ks) {
                const int tp = ks >> 1;
                const unsigned sswz = (unsigned)(((ks & 1) * 4 + quad) << 4);
                const unsigned e00 = A3[tp].x & 0x7FFFu;
                const unsigned e01 = A3[tp].x >> 16;
                const unsigned e10 = A3[tp].y & 0xFFFFu;
                const unsigned e11 = A3[tp].y >> 16;
                uint4 q0 = *(const uint4*)(winc + ((e00 << 4) ^ sswz));
                uint4 q1 = *(const uint4*)(winc + ((e01 << 4) ^ sswz));
                uint4 q2 = *(const uint4*)(winc + ((e10 << 4) ^ sswz));
                uint4 q3 = *(const uint4*)(winc + ((e11 << 4) ^ sswz));
                if (__builtin_expect(__any((int)((A3[tp].x >> 15) & 1u)), 0)) {
                    if ((A3[tp].x >> 15) & 1u) {   // exact fallback, ~never
                        const int tap = kc * 3 + tp;
                        const int qq = qb + m16;
                        const int ky = (tap * 11) >> 5;
                        const int kx = tap - ky * 3;
                        const float oy = offb[(2 * tap) * HW + rowX * 64 + qq];
                        const float ox = offb[(2 * tap + 1) * HW + rowX * 64 + qq];
                        const float py  = oy + (float)(rowX - 1 + ky);
                        const float pxf = ox + (float)(qq - 1 + kx);
                        const int y0 = (int)floorf(py), x0 = (int)floorf(pxf);
                        const int cy0 = min(max(y0, 0), HH - 1);
                        const int cy1 = min(max(y0 + 1, 0), HH - 1);
                        const int cx0 = min(max(x0, 0), WW - 1);
                        const int cx1 = min(max(x0 + 1, 0), WW - 1);
                        const int hoff = (ks & 1) * 64 + quad * 16;
                        q0 = *(const uint4*)(xtb + ((cy0 * 64 + cx0) << 7) + hoff);
                        q1 = *(const uint4*)(xtb + ((cy0 * 64 + cx1) << 7) + hoff);
                        q2 = *(const uint4*)(xtb + ((cy1 * 64 + cx0) << 7) + hoff);
                        q3 = *(const uint4*)(xtb + ((cy1 * 64 + cx1) << 7) + hoff);
                    }
                }
                const __half2 c00 = ch[tp][0], c01 = ch[tp][1];
                const __half2 c10 = ch[tp][2], c11 = ch[tp][3];
                uint4 ov;
                {
                    __half2 v = __hmul2(c00, as_h2(q0.x));
                    v = __hfma2(c01, as_h2(q1.x), v);
                    v = __hfma2(c10, as_h2(q2.x), v);
                    v = __hfma2(c11, as_h2(q3.x), v);
                    ov.x = as_u32(v);
                }
                {
                    __half2 v = __hmul2(c00, as_h2(q0.y));
                    v = __hfma2(c01, as_h2(q1.y), v);
                    v = __hfma2(c10, as_h2(q2.y), v);
                    v = __hfma2(c11, as_h2(q3.y), v);
                    ov.y = as_u32(v);
                }
                {
                    __half2 v = __hmul2(c00, as_h2(q0.z));
                    v = __hfma2(c01, as_h2(q1.z), v);
                    v = __hfma2(c10, as_h2(q2.z), v);
                    v = __hfma2(c11, as_h2(q3.z), v);
                    ov.z = as_u32(v);
                }
                {
                    __half2 v = __hmul2(c00, as_h2(q0.w));
                    v = __hfma2(c01, as_h2(q1.w), v);
                    v = __hfma2(c10, as_h2(q2.w), v);
                    v = __hfma2(c11, as_h2(q3.w), v);
                    ov.w = as_u32(v);
                }
                f16x8 bfrag;
                __builtin_memcpy(&bfrag, &ov, 16);
#pragma unroll
                for (int ot = 0; ot < 4; ++ot) {
                    const f16x8 afrag =
                        *(const f16x8*)(wkc + (ks * 4 + ot) * 512 + lane * 8);
                    acc[ot] = __builtin_amdgcn_mfma_f32_16x16x32_f16(
                        afrag, bfrag, acc[ot], 0, 0, 0);
                }
            }
        }

        float* ob = out + b * (COUT * HW) + rowX * 64 + qb + m16;
#pragma unroll
        for (int ot = 0; ot < 4; ++ot)
#pragma unroll
            for (int r = 0; r < 4; ++r) {
                const int o = ot * 16 + quad * 4 + r;
                ob[o * HW] = acc[ot][r] + bias[o];
            }
    }
}

extern "C" void kernel_launch(void* const* d_in, const int* in_sizes, int n_in,
                              void* d_out, int out_size, void* d_ws,
                              size_t ws_size, hipStream_t stream) {
    const float* x    = (const float*)d_in[0];
    const float* off  = (const float*)d_in[1];
    const float* mask = (const float*)d_in[2];
    const float* w    = (const float*)d_in[3];
    const float* bias = (const float*)d_in[4];
    float* out = (float*)d_out;

    unsigned short* xt = (unsigned short*)d_ws;                     // 8388608 B
    unsigned short* wt = (unsigned short*)((char*)d_ws + 8388608);  // 73728 B

    prep_kernel<<<1024 + 144, 256, 0, stream>>>(x, w, xt, wt);
    dcn_main_kernel<<<256, 512, 0, stream>>>(off, mask, xt, wt, bias, out);
}

// Round 9
// 98.491 us; speedup vs baseline: 1.7880x; 1.2724x over previous
//
#include <hip/hip_runtime.h>
#include <hip/hip_fp16.h>

#define BATCH 16
#define C_IN  64
#define HH    64
#define WW    64
#define COUT  64
#define KK    9
#define HW    4096
#define CK    576
#define WROWS 13    // staged window rows: [R-5, R+7] for the row pair R,R+1
#define WLO   5

typedef _Float16 f16x8 __attribute__((ext_vector_type(8)));
typedef float    f32x4 __attribute__((ext_vector_type(4)));

__device__ __forceinline__ unsigned short f32_to_f16u(float f) {
    _Float16 h = (_Float16)f;       // v_cvt_f16_f32, RNE
    unsigned short u;
    __builtin_memcpy(&u, &h, 2);
    return u;
}

__device__ __forceinline__ __half2 as_h2(unsigned int u) {
    __half2 r; __builtin_memcpy(&r, &u, 4); return r;
}
__device__ __forceinline__ unsigned int as_u32(__half2 v) {
    unsigned int u; __builtin_memcpy(&u, &v, 4); return u;
}

// Fused prep, R16.  R10's tile[64][72] had ~8-16-way LDS WRITE conflicts
// (bank = 16*seg + 4k + c/2 mod 32: seg contributes only {0,16}).  New:
// tile[64][64] (128-B rows, no pad) + 16-B-granule XOR swizzle (chunk ^=
// row&7 — same scheme as main's window, proven).  Each thread covers 4 rows
// 16 APART (scalar dword loads, still 4x64-B coalesced segments/instr) and
// writes ushort2 (channel pair): write banks = cp ^ 4*(row&7) -> 2-way
// (free).  Reads: int4 at (16cs ^ ((xx&7)<<4)) -> slots cs^(xx&7), optimal;
// returns channels 8cs..8cs+7 in order (XOR algebra: chunk ci holds cpairs
// with cp>>2 = ci^(row&7)).  Blocks 1024..1167: w -> wt unchanged.
__global__ __launch_bounds__(256) void prep_kernel(
    const float* __restrict__ x, const float* __restrict__ w,
    unsigned short* __restrict__ xt, unsigned short* __restrict__ wt) {
    __shared__ unsigned short tile[64 * 64];   // row=px (128 B), col=ch, swizzled
    const int t = threadIdx.x;
    const int blk = blockIdx.x;
    if (blk < 1024) {
        const int b = blk >> 6, y = blk & 63;
        const float* xrow = x + ((b * 64) * 64 + y) * 64;
        char* tb = (char*)tile;
#pragma unroll
        for (int it = 0; it < 2; ++it) {
            const int idx = it * 256 + t;
            const int pxb = idx & 15;           // px base
            const int cp  = idx >> 4;           // channel pair 0..31
            const float* c0 = xrow + (2 * cp) * HW;
            const float* c1 = c0 + HW;
#pragma unroll
            for (int m = 0; m < 4; ++m) {
                const int row = pxb + 16 * m;
                const unsigned h0 = f32_to_f16u(c0[row]);
                const unsigned h1 = f32_to_f16u(c1[row]);
                *(unsigned int*)(tb + row * 128 + ((4 * cp) ^ ((row & 7) << 4)))
                    = h0 | (h1 << 16);
            }
        }
        __syncthreads();
#pragma unroll
        for (int it = 0; it < 2; ++it) {
            const int idx = it * 256 + t;
            const int xx = idx >> 3, cs = idx & 7;
            *(int4*)&xt[((b * HW) + y * 64 + xx) * 64 + cs * 8] =
                *(const int4*)(tb + xx * 128 + ((cs * 16) ^ ((xx & 7) << 4)));
        }
    } else {
        const int i = (blk - 1024) * 256 + t;  // 0..36863
        const int j = i & 7;
        const int l = (i >> 3) & 63;
        const int ot = (i >> 9) & 3;
        const int r = i >> 11;           // 0..17
        const int ks = r % 6, kc = r / 6;
        const int o  = ot * 16 + (l & 15);
        const int kk = ks * 32 + (l >> 4) * 8 + j;
        const int tap = kk >> 6, c = kk & 63;
        const int k = kc * 3 + tap;
        wt[i] = f32_to_f16u(w[o * CK + c * KK + k]);
    }
}

// Main = R10 byte-identical (the 96.75 us anchor; VGPR 88, no scratch).
// R14/R15 post-mortem: the 4-row merge hits a 128-VGPR allocator wall with
// ~500 B/thread scratch both attempts -> abandoned.  2-row, 2-round
// structure is the clean configuration.
__global__ __launch_bounds__(512, 1) void dcn_main_kernel(
    const float* __restrict__ offset, const float* __restrict__ mask,
    const unsigned short* __restrict__ xt, const unsigned short* __restrict__ wt,
    const float* __restrict__ bias, float* __restrict__ out) {
    __shared__ __align__(16) unsigned short win[WROWS * 4096];   // 106496 B
    __shared__ __align__(16) int PWw[2][576 * 4];                //  18432 B
    __shared__ __align__(16) unsigned int PWa[2][576 * 4];       //  18432 B

    const int t    = threadIdx.x;
    const int wave = __builtin_amdgcn_readfirstlane(t >> 6);
    const int lane = t & 63;
    const int quad = lane >> 4, m16 = lane & 15;
    const int rw   = wave >> 2;          // row within pair
    const int qb   = (wave & 3) * 16;    // px strip base

    const int blk = blockIdx.x;
    const int xcd = blk & 7;             // L2 image pinning (R2 win)
    const int i6  = blk >> 3;            // 0..63 within XCD
    const int b   = (xcd << 1) | (i6 >> 5);
    const int R   = (i6 & 31) * 2;       // even row of the pair
    const int base = R - WLO;            // window first row (may be <0)

    const float* offb = offset + b * (2 * KK * HW);
    const float* mb   = mask + b * (KK * HW);
    const char* xtb   = (const char*)(xt + b * (HW * 64));

    // ---- Prologue loads first (params vmem oldest; staging stays in
    //      flight under the params compute) ----
    float oyv[3], oxv[3], mkv[3];
#pragma unroll
    for (int p = 0; p < 3; ++p) {
        const int it = p * 512 + t;
        if (it < 1152) {
            const int rsel = it >= 576;
            const int j = it - rsel * 576;
            const int tap = j >> 6, q = j & 63;
            const int rowX = R + rsel;
            oyv[p] = offb[(2 * tap) * HW + rowX * 64 + q];
            oxv[p] = offb[(2 * tap + 1) * HW + rowX * 64 + q];
            mkv[p] = mb[tap * HW + rowX * 64 + q];
        } else { oyv[p] = 0.f; oxv[p] = 0.f; mkv[p] = 0.f; }
    }
    asm volatile("" :: "v"(oyv[0]), "v"(oxv[0]), "v"(mkv[0]),
                       "v"(oyv[1]), "v"(oxv[1]), "v"(mkv[1]),
                       "v"(oyv[2]), "v"(oxv[2]), "v"(mkv[2]));

    // ---- Stage window: 13 rows x 8 KB, async global->LDS, swizzled source.
    //      LDS dest linear (HW rule: base + lane*16); global source carries
    //      the inverse swizzle: chan-block s' of pixel pxl holds global
    //      chan-block s' ^ (pxl&7). ----
    const int pxl = t >> 3;
    const int swb = ((t & 7) ^ (pxl & 7)) << 4;
#pragma unroll
    for (int s = 0; s < WROWS; ++s) {
        const int srcrow = min(max(base + s, 0), HH - 1);
        const char* src = xtb + srcrow * 8192 + pxl * 128 + swb;
        __builtin_amdgcn_global_load_lds(
            (const __attribute__((address_space(1))) unsigned int*)src,
            (__attribute__((address_space(3))) unsigned int*)
                ((char*)win + s * 8192 + t * 16),
            16, 0, 0);
    }
    __builtin_amdgcn_sched_barrier(0);

    // ---- Prologue compute: params for 1152 items (row x tap x q) ----
    //      PWa: per-corner pre-swizzled window byte offset
    //           enc(w) = (w<<7) | ((w&7)<<4);  esc flag in bit 31 of .x
#pragma unroll
    for (int p = 0; p < 3; ++p) {
        const int it = p * 512 + t;
        if (it < 1152) {
            const int rsel = it >= 576;
            const int j = it - rsel * 576;
            const int tap = j >> 6, q = j & 63;
            const int rowX = R + rsel;
            const int ky = (tap * 11) >> 5;      // tap/3 for 0..8
            const int kx = tap - ky * 3;
            const float py  = oyv[p] + (float)(rowX - 1 + ky);
            const float pxf = oxv[p] + (float)(q - 1 + kx);
            const float y0f = floorf(py), x0f = floorf(pxf);
            const float wy = py - y0f, wx = pxf - x0f;
            const int y0 = (int)y0f, x0 = (int)x0f;
            const int y1 = y0 + 1,   x1 = x0 + 1;
            const float vy0 = (y0 >= 0 && y0 < HH) ? 1.f : 0.f;
            const float vy1 = (y1 >= 0 && y1 < HH) ? 1.f : 0.f;
            const float vx0 = (x0 >= 0 && x0 < WW) ? 1.f : 0.f;
            const float vx1 = (x1 >= 0 && x1 < WW) ? 1.f : 0.f;
            const float mk = mkv[p];
            const float w00 = (1.f - wy) * (1.f - wx) * vy0 * vx0 * mk;
            const float w01 = (1.f - wy) * wx         * vy0 * vx1 * mk;
            const float w10 = wy * (1.f - wx)         * vy1 * vx0 * mk;
            const float w11 = wy * wx                 * vy1 * vx1 * mk;
            const int cy0 = min(max(y0, 0), HH - 1), cy1 = min(max(y1, 0), HH - 1);
            const int cx0 = min(max(x0, 0), WW - 1), cx1 = min(max(x1, 0), WW - 1);
            const int sl0 = cy0 - base, sl1 = cy1 - base;
            const unsigned esc = (sl0 < 0) | (sl1 > (WROWS - 1));
            const int c0 = min(max(sl0, 0), WROWS - 1);
            const int c1 = min(max(sl1, 0), WROWS - 1);
            const int wl00 = c0 * 64 + cx0, wl01 = c0 * 64 + cx1;
            const int wl10 = c1 * 64 + cx0, wl11 = c1 * 64 + cx1;
            const unsigned int s00 = f32_to_f16u(w00);
            const unsigned int s01 = f32_to_f16u(w01);
            const unsigned int s10 = f32_to_f16u(w10);
            const unsigned int s11 = f32_to_f16u(w11);
            int4 P0;
            P0.x = (int)(s00 | (s00 << 16));   // (w,w) half2 pairs
            P0.y = (int)(s01 | (s01 << 16));
            P0.z = (int)(s10 | (s10 << 16));
            P0.w = (int)(s11 | (s11 << 16));
            *(int4*)&PWw[rsel][j * 4] = P0;
            uint4 A;
            A.x = (unsigned)((wl00 << 7) | ((wl00 & 7) << 4)) | (esc << 31);
            A.y = (unsigned)((wl01 << 7) | ((wl01 & 7) << 4));
            A.z = (unsigned)((wl10 << 7) | ((wl10 & 7) << 4));
            A.w = (unsigned)((wl11 << 7) | ((wl11 & 7) << 4));
            *(uint4*)&PWa[rsel][j * 4] = A;
        }
    }
    __syncthreads();   // staging (per-wave vmcnt) + params visible

    f32x4 acc[4];
#pragma unroll
    for (int ot = 0; ot < 4; ++ot)
#pragma unroll
        for (int r = 0; r < 4; ++r) acc[ot][r] = 0.f;

    const char* winc = (const char*)win;
    const int rowX = R + rw;

#pragma unroll
    for (int kc = 0; kc < 3; ++kc) {
        const unsigned short* wkc = wt + kc * (6 * 4 * 512);
#pragma unroll
        for (int ks = 0; ks < 6; ++ks) {
            const int tap = kc * 3 + (ks >> 1);
            const int it  = tap * 64 + qb + m16;
            const uint4 A  = *(const uint4*)&PWa[rw][it * 4];  // bcast x4
            const int4  p0 = *(const int4*)&PWw[rw][it * 4];   // bcast x4
            const unsigned sswz = (unsigned)(((ks & 1) * 4 + quad) << 4);
            uint4 q0 = *(const uint4*)(winc + ((A.x & 0x7FFFFFFFu) ^ sswz));
            uint4 q1 = *(const uint4*)(winc + (A.y ^ sswz));
            uint4 q2 = *(const uint4*)(winc + (A.z ^ sswz));
            uint4 q3 = *(const uint4*)(winc + (A.w ^ sswz));
            if (__builtin_expect(__any((int)(A.x >> 31)), 0)) {  // ~never
                if (A.x >> 31) {
                    const int q = qb + m16;
                    const int ky = (tap * 11) >> 5;
                    const int kx = tap - ky * 3;
                    const float oy = offb[(2 * tap) * HW + rowX * 64 + q];
                    const float ox = offb[(2 * tap + 1) * HW + rowX * 64 + q];
                    const float py  = oy + (float)(rowX - 1 + ky);
                    const float pxf = ox + (float)(q - 1 + kx);
                    const int y0 = (int)floorf(py), x0 = (int)floorf(pxf);
                    const int cy0 = min(max(y0, 0), HH - 1);
                    const int cy1 = min(max(y0 + 1, 0), HH - 1);
                    const int cx0 = min(max(x0, 0), WW - 1);
                    const int cx1 = min(max(x0 + 1, 0), WW - 1);
                    const int hoff = (ks & 1) * 64 + quad * 16;
                    q0 = *(const uint4*)(xtb + ((cy0 * 64 + cx0) << 7) + hoff);
                    q1 = *(const uint4*)(xtb + ((cy0 * 64 + cx1) << 7) + hoff);
                    q2 = *(const uint4*)(xtb + ((cy1 * 64 + cx0) << 7) + hoff);
                    q3 = *(const uint4*)(xtb + ((cy1 * 64 + cx1) << 7) + hoff);
                }
            }
            const __half2 c00 = as_h2((unsigned)p0.x);
            const __half2 c01 = as_h2((unsigned)p0.y);
            const __half2 c10 = as_h2((unsigned)p0.z);
            const __half2 c11 = as_h2((unsigned)p0.w);
            uint4 ov;
            {
                __half2 v = __hmul2(c00, as_h2(q0.x));
                v = __hfma2(c01, as_h2(q1.x), v);
                v = __hfma2(c10, as_h2(q2.x), v);
                v = __hfma2(c11, as_h2(q3.x), v);
                ov.x = as_u32(v);
            }
            {
                __half2 v = __hmul2(c00, as_h2(q0.y));
                v = __hfma2(c01, as_h2(q1.y), v);
                v = __hfma2(c10, as_h2(q2.y), v);
                v = __hfma2(c11, as_h2(q3.y), v);
                ov.y = as_u32(v);
            }
            {
                __half2 v = __hmul2(c00, as_h2(q0.z));
                v = __hfma2(c01, as_h2(q1.z), v);
                v = __hfma2(c10, as_h2(q2.z), v);
                v = __hfma2(c11, as_h2(q3.z), v);
                ov.z = as_u32(v);
            }
            {
                __half2 v = __hmul2(c00, as_h2(q0.w));
                v = __hfma2(c01, as_h2(q1.w), v);
                v = __hfma2(c10, as_h2(q2.w), v);
                v = __hfma2(c11, as_h2(q3.w), v);
                ov.w = as_u32(v);
            }
            f16x8 bfrag;
            __builtin_memcpy(&bfrag, &ov, 16);
#pragma unroll
            for (int ot = 0; ot < 4; ++ot) {
                const f16x8 afrag =
                    *(const f16x8*)(wkc + (ks * 4 + ot) * 512 + lane * 8);
                acc[ot] = __builtin_amdgcn_mfma_f32_16x16x32_f16(afrag, bfrag,
                                                                 acc[ot], 0, 0, 0);
            }
        }
    }

    float* ob = out + b * (COUT * HW) + rowX * 64 + qb + m16;
#pragma unroll
    for (int ot = 0; ot < 4; ++ot)
#pragma unroll
        for (int r = 0; r < 4; ++r) {
            const int o = ot * 16 + quad * 4 + r;
            ob[o * HW] = acc[ot][r] + bias[o];
        }
}

extern "C" void kernel_launch(void* const* d_in, const int* in_sizes, int n_in,
                              void* d_out, int out_size, void* d_ws,
                              size_t ws_size, hipStream_t stream) {
    const float* x    = (const float*)d_in[0];
    const float* off  = (const float*)d_in[1];
    const float* mask = (const float*)d_in[2];
    const float* w    = (const float*)d_in[3];
    const float* bias = (const float*)d_in[4];
    float* out = (float*)d_out;

    unsigned short* xt = (unsigned short*)d_ws;                     // 8388608 B
    unsigned short* wt = (unsigned short*)((char*)d_ws + 8388608);  // 73728 B

    prep_kernel<<<1024 + 144, 256, 0, stream>>>(x, w, xt, wt);
    dcn_main_kernel<<<512, 512, 0, stream>>>(off, mask, xt, wt, bias, out);
}